// Round 3
// baseline (326.229 us; speedup 1.0000x reference)
//
#include <hip/hip_runtime.h>

// AttentionFusion: fused = sigmoid(dot(x1-x2, w)) * x1 + (1-sig) * x2, per row.
// N=16384 rows, D=2048 cols, fp32.
//
// R3 = R2 design with native clang vector types so __builtin_nontemporal_store
// compiles (HIP_vector_type float4 is a struct; the builtin needs ext_vector_type).
// One WAVE (64 lanes) per row, 4 waves/block, NO __syncthreads.
// Each lane holds 8 vfloat4 of x1, x2, w in registers (24 loads in flight),
// wave-local shfl_xor butterfly reduce (no LDS), fuse from registers,
// nontemporal stores (fused is never re-read; keep x1/x2 resident in L3).
// R1 block-per-row + barrier variant: 112 us @ 2.4 TB/s reported — barrier
// drain between load and store phases killed MLP.

#define NROWS 16384
#define DCOLS 2048
#define WPB 4  // waves per block

typedef float vfloat4 __attribute__((ext_vector_type(4)));
typedef float vfloat2 __attribute__((ext_vector_type(2)));

__global__ __launch_bounds__(256) void attn_fuse_wave(
    const float* __restrict__ x1,
    const float* __restrict__ x2,
    const float* __restrict__ w,
    float* __restrict__ fused,
    float* __restrict__ alpha)
{
    const int wave = threadIdx.x >> 6;
    const int lane = threadIdx.x & 63;
    const int row  = blockIdx.x * WPB + wave;

    const vfloat4* __restrict__ x1v = (const vfloat4*)(x1 + (size_t)row * DCOLS);
    const vfloat4* __restrict__ x2v = (const vfloat4*)(x2 + (size_t)row * DCOLS);
    const vfloat4* __restrict__ wv  = (const vfloat4*)w;

    // 512 float4 per row / 64 lanes = 8 per lane, stride-64 (coalesced 1 KiB/instr).
    vfloat4 a[8], b[8], wr[8];
    #pragma unroll
    for (int j = 0; j < 8; ++j) a[j]  = x1v[lane + 64 * j];
    #pragma unroll
    for (int j = 0; j < 8; ++j) b[j]  = x2v[lane + 64 * j];
    #pragma unroll
    for (int j = 0; j < 8; ++j) wr[j] = wv[lane + 64 * j];

    // Partial of dot(x1 - x2, w) — only the score difference matters.
    float p = 0.0f;
    #pragma unroll
    for (int j = 0; j < 8; ++j) {
        vfloat4 d = (a[j] - b[j]) * wr[j];
        p += d.x + d.y + d.z + d.w;
    }

    // Wave-64 butterfly reduce: every lane ends with the full sum. No LDS.
    #pragma unroll
    for (int off = 1; off < 64; off <<= 1)
        p += __shfl_xor(p, off, 64);

    const float g = 1.0f / (1.0f + expf(-p));  // alpha1 = sigmoid(s1 - s2)

    // fused = x2 + g*(x1 - x2), straight from registers.
    vfloat4* outv = (vfloat4*)(fused + (size_t)row * DCOLS);
    #pragma unroll
    for (int j = 0; j < 8; ++j) {
        vfloat4 f = b[j] + g * (a[j] - b[j]);
        __builtin_nontemporal_store(f, &outv[lane + 64 * j]);
    }

    if (lane == 0) {
        vfloat2 al;
        al.x = g;
        al.y = 1.0f - g;
        __builtin_nontemporal_store(al, (vfloat2*)(alpha + (size_t)row * 2));
    }
}

extern "C" void kernel_launch(void* const* d_in, const int* in_sizes, int n_in,
                              void* d_out, int out_size, void* d_ws, size_t ws_size,
                              hipStream_t stream)
{
    const float* x1 = (const float*)d_in[0];
    const float* x2 = (const float*)d_in[1];
    const float* w  = (const float*)d_in[2];

    float* fused = (float*)d_out;                  // [N, D]
    float* alpha = fused + (size_t)NROWS * DCOLS;  // [N, 2]

    attn_fuse_wave<<<NROWS / WPB, 256, 0, stream>>>(x1, x2, w, fused, alpha);
}